// Round 9
// baseline (58.490 us; speedup 1.0000x reference)
//
#include <hip/hip_runtime.h>
#include <math.h>

#define LL 4096
#define CC 128
#define SS 64
#define CLEN 32    // steps per chunk (wave)
#define GW 8       // chunks (waves) per group/block
#define NG 16      // groups; NG*GW*CLEN = LL
#define CS 8192    // CC*SS

// ---------------- kernel 1: projections (B, Cm, dtT) + xT (R6 verbatim) ----
// 1024 blocks x 256 thr; block = 4 rows; thread = 1 row x 4 cols.
__global__ __launch_bounds__(256) void k_proj(
    const float* __restrict__ x,
    const float* __restrict__ Bk, const float* __restrict__ Bb,
    const float* __restrict__ Ck, const float* __restrict__ Cb,
    const float* __restrict__ Dk, const float* __restrict__ Db,
    float* __restrict__ Bmat, float* __restrict__ Cmat,
    float* __restrict__ DTmT, float* __restrict__ xT)
{
    __shared__ float xs[CC][4];    // transposed x tile [k][row]
    const int r0 = blockIdx.x * 4;
    const int t = threadIdx.x;
    {
        const int r = t >> 6, k2 = (t & 63) * 2;
        const float2 v = *(const float2*)&x[(r0 + r) * CC + k2];
        xs[k2][r] = v.x; xs[k2 + 1][r] = v.y;
    }
    __syncthreads();
    if (t < CC) {   // emit x transposed [C][L]: k = t, 4 rows contiguous
        *(float4*)&xT[t * LL + r0] = *(const float4*)&xs[t][0];
    }
    const int tc = t & 63, tr = t >> 6;
    const float* Wb; int wstride, wo;
    if (tc < 16)      { Wb = Bk; wstride = SS; wo = 4 * tc; }
    else if (tc < 32) { Wb = Ck; wstride = SS; wo = 4 * tc - 64; }
    else              { Wb = Dk; wstride = CC; wo = 4 * tc - 128; }
    float acc[4] = {0.f, 0.f, 0.f, 0.f};
#pragma unroll 8
    for (int k = 0; k < CC; ++k) {
        const float4 wq = *(const float4*)(Wb + k * wstride + wo);  // L1/L2-hot
        const float xv = xs[k][tr];                                 // broadcast
        acc[0] = fmaf(xv, wq.x, acc[0]);
        acc[1] = fmaf(xv, wq.y, acc[1]);
        acc[2] = fmaf(xv, wq.z, acc[2]);
        acc[3] = fmaf(xv, wq.w, acc[3]);
    }
    const int row = r0 + tr;
    if (tc < 16) {
        const float4 o = make_float4(acc[0] + 1.0f + Bb[wo], acc[1] + 1.0f + Bb[wo+1],
                                     acc[2] + 1.0f + Bb[wo+2], acc[3] + 1.0f + Bb[wo+3]);
        *(float4*)&Bmat[row * SS + wo] = o;
    } else if (tc < 32) {
        const float4 o = make_float4(acc[0] + Cb[wo], acc[1] + Cb[wo+1],
                                     acc[2] + Cb[wo+2], acc[3] + Cb[wo+3]);
        *(float4*)&Cmat[row * SS + wo] = o;
    } else {
#pragma unroll
        for (int j = 0; j < 4; ++j) {
            const float z = acc[j] + Db[wo + j] + 0.000244140625f;
            const float sp = fmaxf(z, 0.0f) + log1pf(__expf(-fabsf(z)));  // stable softplus
            DTmT[(wo + j) * LL + row] = sp;
        }
    }
}

// ------- kernel 2: group aggregates (R8, occupancy raised to 8 waves/EU) ----
// block = (c, g): 2048 blocks x 512 thr = 8 waves = 8 chunks of group g. lane = s.
__global__ __launch_bounds__(512, 8) void k_sweep1(
    const float* __restrict__ xT, const float* __restrict__ A_log,
    const float* __restrict__ Bmat, const float* __restrict__ DTmT,
    float* __restrict__ Ga, float* __restrict__ Gu)
{
    __shared__ float2 agg[GW][SS];
    const int lane = threadIdx.x & 63;
    const int w = __builtin_amdgcn_readfirstlane(threadIdx.x >> 6);
    const int c = blockIdx.x >> 4;          // SGPR
    const int g = blockIdx.x & (NG - 1);    // SGPR
    const int j = c * SS + lane;
    const float A = -__expf(A_log[j]);
    const float invA = 1.0f / A;
    const int l0 = (g * GW + w) * CLEN;
    const float* dtp = DTmT + c * LL + l0;  // uniform + contiguous -> s_load batches
    const float* xp  = xT   + c * LL + l0;
    const float* Bp  = Bmat + l0 * SS + lane;
    float ap = 1.0f, uc = 0.0f;
#pragma unroll
    for (int i = 0; i < CLEN; ++i) {
        const float At = __expf(A * dtp[i]);
        const float u  = (At - 1.0f) * invA * (Bp[i * SS] * xp[i]);
        ap *= At;
        uc = fmaf(At, uc, u);
    }
    agg[w][lane] = make_float2(ap, uc);
    __syncthreads();
    if (w == 0) {   // compose 8 chunks in time order -> group aggregate
        float ga = 1.0f, gu = 0.0f;
#pragma unroll
        for (int k = 0; k < GW; ++k) {
            const float2 t = agg[k][lane];
            gu = fmaf(t.x, gu, t.y);
            ga *= t.x;
        }
        Ga[g * CS + j] = ga;
        Gu[g * CS + j] = gu;
    }
}

// ------- kernel 3: preloaded group-scan + reg-cached rewalk + emit (R8) ----
// block = (c, g): 2048 blocks x 512 thr = 8 waves = 8 chunks of group g. lane = s.
__global__ __launch_bounds__(512, 4) void k_emit(
    const float* __restrict__ xT, const float* __restrict__ A_log,
    const float* __restrict__ Bmat, const float* __restrict__ Cmat,
    const float* __restrict__ DTmT,
    const float* __restrict__ Ga, const float* __restrict__ Gu,
    float* __restrict__ y)
{
    __shared__ float2 agg[GW][SS];
    const int lane = threadIdx.x & 63;
    const int w = __builtin_amdgcn_readfirstlane(threadIdx.x >> 6);
    const int c = blockIdx.x >> 4;          // SGPR
    const int g = blockIdx.x & (NG - 1);    // SGPR
    const int j = c * SS + lane;
    const float A = -__expf(A_log[j]);
    const float invA = 1.0f / A;
    // cross-group exclusive prefix: 15 INDEPENDENT coalesced load-pairs,
    // then a predicated 15-step fma chain.
    float hg = 0.0f;
    {
        float gar[NG - 1], gur[NG - 1];
#pragma unroll
        for (int gg = 0; gg < NG - 1; ++gg) {
            gar[gg] = Ga[gg * CS + j];
            gur[gg] = Gu[gg * CS + j];
        }
#pragma unroll
        for (int gg = 0; gg < NG - 1; ++gg)
            hg = (gg < g) ? fmaf(gar[gg], hg, gur[gg]) : hg;
    }
    const int l0 = (g * GW + w) * CLEN;
    const float* dtp = DTmT + c * LL + l0;
    const float* xp  = xT   + c * LL + l0;
    const float* Bp  = Bmat + l0 * SS + lane;
    const float* Cp  = Cmat + l0 * SS + lane;
    // pass 1: chunk aggregate, caching at[] / uu[] in registers
    float at[CLEN], uu[CLEN];
    {
        float ap = 1.0f, uc = 0.0f;
#pragma unroll
        for (int i = 0; i < CLEN; ++i) {
            at[i] = __expf(A * dtp[i]);
            uu[i] = (at[i] - 1.0f) * invA * (Bp[i * SS] * xp[i]);
            ap *= at[i];
            uc = fmaf(at[i], uc, uu[i]);
        }
        agg[w][lane] = make_float2(ap, uc);
    }
    __syncthreads();
    // in-block exclusive prefix over chunks 0..w-1 (trip count wave-uniform)
    float ea = 1.0f, eu = 0.0f;
    for (int k = 0; k < w; ++k) {
        const float2 t = agg[k][lane];
        eu = fmaf(t.x, eu, t.y);
        ea *= t.x;
    }
    float h = fmaf(ea, hg, eu);
    // pass 2: rewalk from registers (no reload, no re-exp); uu[] becomes p[]
#pragma unroll
    for (int i = 0; i < CLEN; ++i) {
        h = fmaf(at[i], h, uu[i]);
        uu[i] = Cp[i * SS] * h;
    }
    // 32-row x 64-lane register-halving transpose-reduce
#pragma unroll
    for (int k = 0; k < 5; ++k) {
        const int d = 1 << k;
        const bool hi = (lane & d) != 0;
#pragma unroll
        for (int i2 = 0; i2 < (CLEN >> (k + 1)); ++i2) {
            const float a = uu[2 * i2], b = uu[2 * i2 + 1];
            const float send = hi ? a : b;
            const float t = __shfl_xor(send, d, 64);
            uu[i2] = (hi ? b : a) + t;
        }
    }
    const float t = __shfl_xor(uu[0], 32, 64);
    const float yv = uu[0] + t;
    if (lane < 32) y[(l0 + lane) * CC + c] = yv;
}

extern "C" void kernel_launch(void* const* d_in, const int* in_sizes, int n_in,
                              void* d_out, int out_size, void* d_ws, size_t ws_size,
                              hipStream_t stream)
{
    const float* x  = (const float*)d_in[0];
    const float* Al = (const float*)d_in[1];
    const float* Bk = (const float*)d_in[2];
    const float* Bb = (const float*)d_in[3];
    const float* Ck = (const float*)d_in[4];
    const float* Cb = (const float*)d_in[5];
    const float* Dk = (const float*)d_in[6];
    const float* Db = (const float*)d_in[7];
    float* y  = (float*)d_out;
    float* ws = (float*)d_ws;

    float* Bmat = ws;                    // [L][S]   1 MB
    float* Cmat = Bmat + LL * SS;        // [L][S]   1 MB
    float* DTmT = Cmat + LL * SS;        // [C][L]   2 MB
    float* xT   = DTmT + CC * LL;        // [C][L]   2 MB
    float* Ga   = xT   + CC * LL;        // [NG][CS] 0.5 MB
    float* Gu   = Ga   + NG * CS;        // [NG][CS] 0.5 MB

    k_proj  <<<LL / 4,  256, 0, stream>>>(x, Bk, Bb, Ck, Cb, Dk, Db, Bmat, Cmat, DTmT, xT);
    k_sweep1<<<CC * NG, 512, 0, stream>>>(xT, Al, Bmat, DTmT, Ga, Gu);
    k_emit  <<<CC * NG, 512, 0, stream>>>(xT, Al, Bmat, Cmat, DTmT, Ga, Gu, y);
}

// Round 10
// 51.771 us; speedup vs baseline: 1.1298x; 1.1298x over previous
//
#include <hip/hip_runtime.h>
#include <math.h>

#define LL 4096
#define CC 128
#define SS 64
#define CLEN 32    // steps per chunk (wave)
#define GW 8       // chunks (waves) per group/block
#define NG 16      // groups; NG*GW*CLEN = LL
#define CS 8192    // CC*SS
#define LOG2E 1.44269504088896f

// ---------------- kernel 1: projections, split by output half ----------------
// 512 blocks x 256 thr; stripe = bid>>1 (16 rows), half = bid&1.
// half 0: B+C GEMM (128 cols). half 1: dt GEMM (128 cols) + xT emission.
// thread = 4 rows x 2 cols.
__global__ __launch_bounds__(256) void k_proj(
    const float* __restrict__ x,
    const float* __restrict__ Bk, const float* __restrict__ Bb,
    const float* __restrict__ Ck, const float* __restrict__ Cb,
    const float* __restrict__ Dk, const float* __restrict__ Db,
    float* __restrict__ Bmat, float* __restrict__ Cmat,
    float* __restrict__ DTmT, float* __restrict__ xT)
{
    __shared__ float xs[CC][20];   // transposed x tile [k][row]; 80B rows, 16B-aligned
    const int stripe = blockIdx.x >> 1;
    const int half   = blockIdx.x & 1;
    const int r0 = stripe * 16;
    const int t = threadIdx.x;
    {
        const int r = t >> 4, k8 = (t & 15) * 8;
        const float4 v0 = *(const float4*)&x[(r0 + r) * CC + k8];
        const float4 v1 = *(const float4*)&x[(r0 + r) * CC + k8 + 4];
        xs[k8+0][r] = v0.x; xs[k8+1][r] = v0.y; xs[k8+2][r] = v0.z; xs[k8+3][r] = v0.w;
        xs[k8+4][r] = v1.x; xs[k8+5][r] = v1.y; xs[k8+6][r] = v1.z; xs[k8+7][r] = v1.w;
    }
    __syncthreads();
    const int tc = t & 63, tr = t >> 6;
    const int c2 = 2 * tc;                 // first of this thread's 2 cols
    const int rb = r0 + 4 * tr;
    if (half == 1) {
        // emit x transposed [C][L]
        const int k = t >> 1, h8 = (t & 1) * 8;
        const float4 a = *(const float4*)&xs[k][h8];
        const float4 b = *(const float4*)&xs[k][h8 + 4];
        *(float4*)&xT[k * LL + r0 + h8]     = a;
        *(float4*)&xT[k * LL + r0 + h8 + 4] = b;
        // dt GEMM: W = Dk, stride CC
        float acc[4][2];
#pragma unroll
        for (int r = 0; r < 4; ++r) { acc[r][0] = 0.f; acc[r][1] = 0.f; }
        const float* W = Dk + c2;
        for (int k2 = 0; k2 < CC; ++k2) {
            const float2 wq = *(const float2*)(W + k2 * CC);
            const float4 xq = *(const float4*)&xs[k2][4 * tr];
            const float xv[4] = {xq.x, xq.y, xq.z, xq.w};
#pragma unroll
            for (int r = 0; r < 4; ++r) {
                acc[r][0] = fmaf(xv[r], wq.x, acc[r][0]);
                acc[r][1] = fmaf(xv[r], wq.y, acc[r][1]);
            }
        }
#pragma unroll
        for (int j = 0; j < 2; ++j) {
            const float bj = Db[c2 + j] + 0.000244140625f;
            float sp[4];
#pragma unroll
            for (int r = 0; r < 4; ++r) {
                const float z = acc[r][j] + bj;
                sp[r] = fmaxf(z, 0.0f) + log1pf(__expf(-fabsf(z)));  // stable softplus
            }
            *(float4*)&DTmT[(c2 + j) * LL + rb] = make_float4(sp[0], sp[1], sp[2], sp[3]);
        }
    } else {
        // B (cols 0..63) / Cm (cols 64..127) GEMM: stride SS
        const bool isB = (c2 < 64);
        const int wo = isB ? c2 : (c2 - 64);
        const float* W = (isB ? Bk : Ck) + wo;
        const float add = isB ? 1.0f : 0.0f;
        const float* bb = isB ? Bb : Cb;
        float* dst = isB ? Bmat : Cmat;
        float acc[4][2];
#pragma unroll
        for (int r = 0; r < 4; ++r) { acc[r][0] = 0.f; acc[r][1] = 0.f; }
        for (int k2 = 0; k2 < CC; ++k2) {
            const float2 wq = *(const float2*)(W + k2 * SS);
            const float4 xq = *(const float4*)&xs[k2][4 * tr];
            const float xv[4] = {xq.x, xq.y, xq.z, xq.w};
#pragma unroll
            for (int r = 0; r < 4; ++r) {
                acc[r][0] = fmaf(xv[r], wq.x, acc[r][0]);
                acc[r][1] = fmaf(xv[r], wq.y, acc[r][1]);
            }
        }
        const float b0 = add + bb[wo], b1 = add + bb[wo + 1];
#pragma unroll
        for (int r = 0; r < 4; ++r) {
            const float2 o = make_float2(acc[r][0] + b0, acc[r][1] + b1);
            *(float2*)&dst[(rb + r) * SS + wo] = o;
        }
    }
}

// ------- kernel 2: group aggregates (exp2-folded, float2 GaGu) -------
// block = (c, g): 2048 blocks x 512 thr = 8 waves = 8 chunks of group g. lane = s.
__global__ __launch_bounds__(512, 4) void k_sweep1(
    const float* __restrict__ xT, const float* __restrict__ A_log,
    const float* __restrict__ Bmat, const float* __restrict__ DTmT,
    float2* __restrict__ GaGu)
{
    __shared__ float2 agg[GW][SS];
    const int lane = threadIdx.x & 63;
    const int w = __builtin_amdgcn_readfirstlane(threadIdx.x >> 6);
    const int c = blockIdx.x >> 4;          // SGPR
    const int g = blockIdx.x & (NG - 1);    // SGPR
    const int j = c * SS + lane;
    const float A = -__expf(A_log[j]);
    const float A2 = A * LOG2E;             // fold log2e: At = 2^(A2*dt)
    const float invA = 1.0f / A;
    const int l0 = (g * GW + w) * CLEN;
    const float* dtp = DTmT + c * LL + l0;  // uniform + contiguous -> s_load batches
    const float* xp  = xT   + c * LL + l0;
    const float* Bp  = Bmat + l0 * SS + lane;
    float ap = 1.0f, uc = 0.0f;
#pragma unroll
    for (int i = 0; i < CLEN; ++i) {
        const float At = __builtin_amdgcn_exp2f(A2 * dtp[i]);
        const float u  = (At - 1.0f) * invA * (Bp[i * SS] * xp[i]);
        ap *= At;
        uc = fmaf(At, uc, u);
    }
    agg[w][lane] = make_float2(ap, uc);
    __syncthreads();
    if (w == 0) {   // compose 8 chunks in time order -> group aggregate
        float ga = 1.0f, gu = 0.0f;
#pragma unroll
        for (int k = 0; k < GW; ++k) {
            const float2 t = agg[k][lane];
            gu = fmaf(t.x, gu, t.y);
            ga *= t.x;
        }
        GaGu[g * CS + j] = make_float2(ga, gu);
    }
}

// ------- kernel 3: preloaded group-scan + reg-cached rewalk + emit -------
// block = (c, g): 2048 blocks x 512 thr = 8 waves = 8 chunks of group g. lane = s.
__global__ __launch_bounds__(512, 4) void k_emit(
    const float* __restrict__ xT, const float* __restrict__ A_log,
    const float* __restrict__ Bmat, const float* __restrict__ Cmat,
    const float* __restrict__ DTmT,
    const float2* __restrict__ GaGu,
    float* __restrict__ y)
{
    __shared__ float2 agg[GW][SS];
    const int lane = threadIdx.x & 63;
    const int w = __builtin_amdgcn_readfirstlane(threadIdx.x >> 6);
    const int c = blockIdx.x >> 4;          // SGPR
    const int g = blockIdx.x & (NG - 1);    // SGPR
    const int j = c * SS + lane;
    const float A = -__expf(A_log[j]);
    const float A2 = A * LOG2E;
    const float invA = 1.0f / A;
    // cross-group exclusive prefix: 15 INDEPENDENT coalesced float2 loads,
    // then a predicated 15-step fma chain.
    float hg = 0.0f;
    {
        float2 ggr[NG - 1];
#pragma unroll
        for (int gg = 0; gg < NG - 1; ++gg) ggr[gg] = GaGu[gg * CS + j];
#pragma unroll
        for (int gg = 0; gg < NG - 1; ++gg)
            hg = (gg < g) ? fmaf(ggr[gg].x, hg, ggr[gg].y) : hg;
    }
    const int l0 = (g * GW + w) * CLEN;
    const float* dtp = DTmT + c * LL + l0;
    const float* xp  = xT   + c * LL + l0;
    const float* Bp  = Bmat + l0 * SS + lane;
    const float* Cp  = Cmat + l0 * SS + lane;
    // pass 1: chunk aggregate, caching at[] / uu[] in registers
    float at[CLEN], uu[CLEN];
    {
        float ap = 1.0f, uc = 0.0f;
#pragma unroll
        for (int i = 0; i < CLEN; ++i) {
            at[i] = __builtin_amdgcn_exp2f(A2 * dtp[i]);
            uu[i] = (at[i] - 1.0f) * invA * (Bp[i * SS] * xp[i]);
            ap *= at[i];
            uc = fmaf(at[i], uc, uu[i]);
        }
        agg[w][lane] = make_float2(ap, uc);
    }
    __syncthreads();
    // in-block exclusive prefix over chunks 0..w-1 (trip count wave-uniform)
    float ea = 1.0f, eu = 0.0f;
    for (int k = 0; k < w; ++k) {
        const float2 t = agg[k][lane];
        eu = fmaf(t.x, eu, t.y);
        ea *= t.x;
    }
    float h = fmaf(ea, hg, eu);
    // pass 2: rewalk from registers (no reload, no re-exp); uu[] becomes p[]
#pragma unroll
    for (int i = 0; i < CLEN; ++i) {
        h = fmaf(at[i], h, uu[i]);
        uu[i] = Cp[i * SS] * h;
    }
    // 32-row x 64-lane register-halving transpose-reduce
#pragma unroll
    for (int k = 0; k < 5; ++k) {
        const int d = 1 << k;
        const bool hi = (lane & d) != 0;
#pragma unroll
        for (int i2 = 0; i2 < (CLEN >> (k + 1)); ++i2) {
            const float a = uu[2 * i2], b = uu[2 * i2 + 1];
            const float send = hi ? a : b;
            const float t = __shfl_xor(send, d, 64);
            uu[i2] = (hi ? b : a) + t;
        }
    }
    const float t = __shfl_xor(uu[0], 32, 64);
    const float yv = uu[0] + t;
    if (lane < 32) y[(l0 + lane) * CC + c] = yv;
}

extern "C" void kernel_launch(void* const* d_in, const int* in_sizes, int n_in,
                              void* d_out, int out_size, void* d_ws, size_t ws_size,
                              hipStream_t stream)
{
    const float* x  = (const float*)d_in[0];
    const float* Al = (const float*)d_in[1];
    const float* Bk = (const float*)d_in[2];
    const float* Bb = (const float*)d_in[3];
    const float* Ck = (const float*)d_in[4];
    const float* Cb = (const float*)d_in[5];
    const float* Dk = (const float*)d_in[6];
    const float* Db = (const float*)d_in[7];
    float* y  = (float*)d_out;
    float* ws = (float*)d_ws;

    float*  Bmat = ws;                    // [L][S]   1 MB
    float*  Cmat = Bmat + LL * SS;        // [L][S]   1 MB
    float*  DTmT = Cmat + LL * SS;        // [C][L]   2 MB
    float*  xT   = DTmT + CC * LL;        // [C][L]   2 MB
    float2* GaGu = (float2*)(xT + CC * LL);  // [NG][CS] 1 MB

    k_proj  <<<2 * (LL / 16), 256, 0, stream>>>(x, Bk, Bb, Ck, Cb, Dk, Db, Bmat, Cmat, DTmT, xT);
    k_sweep1<<<CC * NG,       512, 0, stream>>>(xT, Al, Bmat, DTmT, GaGu);
    k_emit  <<<CC * NG,       512, 0, stream>>>(xT, Al, Bmat, Cmat, DTmT, GaGu, y);
}